// Round 1
// baseline (1181.493 us; speedup 1.0000x reference)
//
#include <hip/hip_runtime.h>
#include <math.h>

#define BB 4
#define C 256
#define H 64
#define W 64
#define HW 4096
#define HO 128
#define WO 128
#define HWO 16384
#define EMB 64

// ---------------------------------------------------------------------------
// K1: transpose weights into inner-loop-friendly layouts
//   wt_cen/wt_cde: [c][e] (256x64)  -> 64 consecutive weights per channel
//   wt_ce:         [e][dy][dx][q]   -> 25 consecutive weights per (e,dy,dx)
// ---------------------------------------------------------------------------
__global__ void k_prep(const float* __restrict__ w_cen,
                       const float* __restrict__ w_cde,
                       const float* __restrict__ w_ce,
                       float* __restrict__ wt_cen,
                       float* __restrict__ wt_cde,
                       float* __restrict__ wt_ce) {
    const int n1 = C * EMB;          // 16384
    const int n3 = EMB * 9 * 25;     // 14400
    for (int idx = blockIdx.x * blockDim.x + threadIdx.x; idx < n1;
         idx += gridDim.x * blockDim.x) {
        int e = idx & 63, c = idx >> 6;
        wt_cen[idx] = w_cen[e * C + c];
        wt_cde[idx] = w_cde[e * C + c];
    }
    for (int idx = blockIdx.x * blockDim.x + threadIdx.x; idx < n3;
         idx += gridDim.x * blockDim.x) {
        int q = idx % 25; int r = idx / 25;
        int dx = r % 3; r /= 3; int dy = r % 3; int e = r / 3;
        wt_ce[idx] = w_ce[((q * EMB + e) * 3 + dy) * 3 + dx];
    }
}

// ---------------------------------------------------------------------------
// K2: blocks [0,128): dec = conv1x1(de, w_cde)  (no bias), e-split x2
//     blocks [128,192): gate_lr = sigmoid(conv1x1(de, w_gate) + b_gate)
// ---------------------------------------------------------------------------
__global__ __launch_bounds__(256) void k_dec_gate(
        const float* __restrict__ de, const float* __restrict__ wt_cde,
        const float* __restrict__ w_gate, const float* __restrict__ b_gate,
        float* __restrict__ dec, float* __restrict__ gate_lr) {
    int t = threadIdx.x;
    if (blockIdx.x < 128) {
        int h  = (t >> 6) & 1;                    // wave-uniform e-half
        int px = (t & 63) | ((t >> 7) << 6);
        int gp = blockIdx.x * 128 + px;           // 0..16383
        int b = gp >> 12, p = gp & 4095;
        int e0 = h * 32;
        float acc[32];
        #pragma unroll
        for (int e = 0; e < 32; e++) acc[e] = 0.f;
        const float* dptr = de + (size_t)b * C * HW + p;
        for (int c = 0; c < C; c++) {
            float v = dptr[(size_t)c * HW];
            const float* w = wt_cde + c * EMB + e0;   // wave-uniform -> SMEM
            #pragma unroll
            for (int e = 0; e < 32; e++) acc[e] += w[e] * v;
        }
        float* o = dec + ((size_t)b * EMB + e0) * HW + p;
        #pragma unroll
        for (int e = 0; e < 32; e++) o[(size_t)e * HW] = acc[e];
    } else {
        int gid = (blockIdx.x - 128) * 256 + t;   // 0..16383
        int b = gid >> 12, p = gid & 4095;
        float acc = b_gate[0];
        const float* dptr = de + (size_t)b * C * HW + p;
        for (int c = 0; c < C; c++) acc += dptr[(size_t)c * HW] * w_gate[c];
        gate_lr[gid] = 1.f / (1.f + expf(-acc));
    }
}

// ---------------------------------------------------------------------------
// K3: enc = conv1x1(en, w_cen) + b_cen  (hi-res grid), e-split x2
// ---------------------------------------------------------------------------
__global__ __launch_bounds__(256) void k_enc(
        const float* __restrict__ en, const float* __restrict__ wt_cen,
        const float* __restrict__ b_cen, float* __restrict__ enc) {
    int t = threadIdx.x;
    int h  = (t >> 6) & 1;
    int px = (t & 63) | ((t >> 7) << 6);
    int gp = blockIdx.x * 128 + px;               // 0..65535
    int b = gp >> 14, p = gp & 16383;
    int e0 = h * 32;
    float acc[32];
    #pragma unroll
    for (int e = 0; e < 32; e++) acc[e] = b_cen[e0 + e];
    const float* eptr = en + (size_t)b * C * HWO + p;
    for (int c = 0; c < C; c++) {
        float v = eptr[(size_t)c * HWO];
        const float* w = wt_cen + c * EMB + e0;
        #pragma unroll
        for (int e = 0; e < 32; e++) acc[e] += w[e] * v;
    }
    float* o = enc + ((size_t)b * EMB + e0) * HWO + p;
    #pragma unroll
    for (int e = 0; e < 32; e++) o[(size_t)e * HWO] = acc[e];
}

// ---------------------------------------------------------------------------
// K4: 3x3 conv 64->25 (pad=1) with bias, e-split x2 + LDS combine.
//   blocks [0,512):   on enc (128x128) -> tmp1
//   blocks [512,640): on dec (64x64)   -> tmp2
// ---------------------------------------------------------------------------
__global__ __launch_bounds__(256) void k_conv3(
        const float* __restrict__ enc, const float* __restrict__ dec,
        const float* __restrict__ wt_ce, const float* __restrict__ b_ce,
        float* __restrict__ tmp1, float* __restrict__ tmp2) {
    __shared__ float lds[2][128][27];             // 27 pad: odd stride, no 4-way conflicts
    int t = threadIdx.x;
    int h  = (t >> 6) & 1;
    int px = (t & 63) | ((t >> 7) << 6);
    bool hi = blockIdx.x < 512;
    const float* src; float* dst;
    int b, p, y, x, width, hwsz;
    if (hi) {
        int gp = blockIdx.x * 128 + px;
        b = gp >> 14; p = gp & 16383; y = p >> 7; x = p & 127;
        width = WO; hwsz = HWO; src = enc; dst = tmp1;
    } else {
        int gp = (blockIdx.x - 512) * 128 + px;
        b = gp >> 12; p = gp & 4095; y = p >> 6; x = p & 63;
        width = W; hwsz = HW; src = dec; dst = tmp2;
    }
    float acc[25];
    #pragma unroll
    for (int q = 0; q < 25; q++) acc[q] = 0.f;
    const float* sbase = src + ((size_t)b * EMB + h * 32) * hwsz;
    for (int e = 0; e < 32; e++) {
        const float* ebase = sbase + (size_t)e * hwsz;
        const float* wbase = wt_ce + ((h * 32 + e) * 9) * 25;
        #pragma unroll
        for (int dy = 0; dy < 3; dy++) {
            int yy = y + dy - 1;
            if ((unsigned)yy < (unsigned)width) {     // square grids: height==width
                #pragma unroll
                for (int dx = 0; dx < 3; dx++) {
                    int xx = x + dx - 1;
                    if ((unsigned)xx < (unsigned)width) {
                        float v = ebase[yy * width + xx];
                        const float* wq = wbase + (dy * 3 + dx) * 25;
                        #pragma unroll
                        for (int q = 0; q < 25; q++) acc[q] += wq[q] * v;
                    }
                }
            }
        }
    }
    #pragma unroll
    for (int q = 0; q < 25; q++) lds[h][px][q] = acc[q];
    __syncthreads();
    if (h == 0) {
        float* o = dst + (size_t)b * 25 * hwsz + p;
        #pragma unroll
        for (int q = 0; q < 25; q++)
            o[(size_t)q * hwsz] = lds[0][px][q] + lds[1][px][q] + b_ce[q];
    }
}

// ---------------------------------------------------------------------------
// K5: logits = tmp1 + up2(tmp2)  (each already contains b_ce -> doubled bias,
//     matching reference); softmax over 25; CARAFE over 5x5 window of de;
//     out = gate*en + (1-gate)*carafe
// ---------------------------------------------------------------------------
__global__ __launch_bounds__(256) void k_final(
        const float* __restrict__ en, const float* __restrict__ de,
        const float* __restrict__ tmp1, const float* __restrict__ tmp2,
        const float* __restrict__ gate_lr, float* __restrict__ out) {
    int gid = blockIdx.x * 256 + threadIdx.x;     // 0..65535
    int b = gid >> 14, p = gid & 16383;
    int i = p >> 7, j = p & 127;
    int yl = i >> 1, xl = j >> 1;
    int pl = yl * W + xl;
    float kern[25];
    float m = -1e30f;
    #pragma unroll
    for (int q = 0; q < 25; q++) {
        float l = tmp1[((size_t)b * 25 + q) * HWO + p]
                + tmp2[((size_t)b * 25 + q) * HW + pl];
        kern[q] = l;
        m = fmaxf(m, l);
    }
    float s = 0.f;
    #pragma unroll
    for (int q = 0; q < 25; q++) { kern[q] = expf(kern[q] - m); s += kern[q]; }
    float inv = 1.f / s;
    #pragma unroll
    for (int q = 0; q < 25; q++) kern[q] *= inv;
    float g = gate_lr[b * HW + pl];
    const float* dbase = de + (size_t)b * C * HW;
    const float* ebase = en + (size_t)b * C * HWO + p;
    float* obase = out + (size_t)b * C * HWO + p;
    for (int c = 0; c < C; c++) {
        const float* dc = dbase + (size_t)c * HW;
        float acc = 0.f;
        #pragma unroll
        for (int dy = 0; dy < 5; dy++) {
            int yy = yl + dy - 2;
            if ((unsigned)yy < (unsigned)H) {
                const float* row = dc + yy * W;
                #pragma unroll
                for (int dx = 0; dx < 5; dx++) {
                    int xx = xl + dx - 2;
                    if ((unsigned)xx < (unsigned)W)
                        acc += kern[dy * 5 + dx] * row[xx];
                }
            }
        }
        float ev = ebase[(size_t)c * HWO];
        obase[(size_t)c * HWO] = g * ev + (1.f - g) * acc;
    }
}

extern "C" void kernel_launch(void* const* d_in, const int* in_sizes, int n_in,
                              void* d_out, int out_size, void* d_ws, size_t ws_size,
                              hipStream_t stream) {
    const float* en     = (const float*)d_in[0];
    const float* de     = (const float*)d_in[1];
    const float* w_gate = (const float*)d_in[2];
    const float* b_gate = (const float*)d_in[3];
    const float* w_cen  = (const float*)d_in[4];
    const float* b_cen  = (const float*)d_in[5];
    const float* w_cde  = (const float*)d_in[6];
    const float* w_ce   = (const float*)d_in[7];
    const float* b_ce   = (const float*)d_in[8];
    float* out = (float*)d_out;

    float* ws      = (float*)d_ws;
    float* wt_cen  = ws;                    // 16384
    float* wt_cde  = wt_cen + 16384;        // 16384
    float* wt_ce   = wt_cde + 16384;        // 14400
    float* gate_lr = wt_ce + 14400;         // 16384
    float* dec     = gate_lr + 16384;       // 4*64*4096   = 1048576
    float* enc     = dec + 1048576;         // 4*64*16384  = 4194304
    float* tmp1    = enc + 4194304;         // 4*25*16384  = 1638400
    float* tmp2    = tmp1 + 1638400;        // 4*25*4096   = 409600
    // total ~29.4 MB of ws

    k_prep<<<64, 256, 0, stream>>>(w_cen, w_cde, w_ce, wt_cen, wt_cde, wt_ce);
    k_dec_gate<<<192, 256, 0, stream>>>(de, wt_cde, w_gate, b_gate, dec, gate_lr);
    k_enc<<<512, 256, 0, stream>>>(en, wt_cen, b_cen, enc);
    k_conv3<<<640, 256, 0, stream>>>(enc, dec, wt_ce, b_ce, tmp1, tmp2);
    k_final<<<256, 256, 0, stream>>>(en, de, tmp1, tmp2, gate_lr, out);
}

// Round 2
// 609.940 us; speedup vs baseline: 1.9371x; 1.9371x over previous
//
#include <hip/hip_runtime.h>
#include <math.h>

#define BB 4
#define C 256
#define H 64
#define W 64
#define HW 4096
#define HO 128
#define WO 128
#define HWO 16384
#define EMB 64

// ---------------------------------------------------------------------------
// K1: transpose weights into inner-loop-friendly layouts
//   wt_cen/wt_cde: [c][e] (256x64)  -> 64 consecutive weights per channel
//   wt_ce:         [e][dy][dx][q]   -> 25 consecutive weights per (e,dy,dx)
// ---------------------------------------------------------------------------
__global__ void k_prep(const float* __restrict__ w_cen,
                       const float* __restrict__ w_cde,
                       const float* __restrict__ w_ce,
                       float* __restrict__ wt_cen,
                       float* __restrict__ wt_cde,
                       float* __restrict__ wt_ce) {
    const int n1 = C * EMB;          // 16384
    const int n3 = EMB * 9 * 25;     // 14400
    for (int idx = blockIdx.x * blockDim.x + threadIdx.x; idx < n1;
         idx += gridDim.x * blockDim.x) {
        int e = idx & 63, c = idx >> 6;
        wt_cen[idx] = w_cen[e * C + c];
        wt_cde[idx] = w_cde[e * C + c];
    }
    for (int idx = blockIdx.x * blockDim.x + threadIdx.x; idx < n3;
         idx += gridDim.x * blockDim.x) {
        int q = idx % 25; int r = idx / 25;
        int dx = r % 3; r /= 3; int dy = r % 3; int e = r / 3;
        wt_ce[idx] = w_ce[((q * EMB + e) * 3 + dy) * 3 + dx];
    }
}

// ---------------------------------------------------------------------------
// K2: blocks [0,128): dec = conv1x1(de, w_cde)  (no bias), e-split x2
//     blocks [128,192): gate_lr = sigmoid(conv1x1(de, w_gate) + b_gate)
// ---------------------------------------------------------------------------
__global__ __launch_bounds__(256) void k_dec_gate(
        const float* __restrict__ de, const float* __restrict__ wt_cde,
        const float* __restrict__ w_gate, const float* __restrict__ b_gate,
        float* __restrict__ dec, float* __restrict__ gate_lr) {
    int t = threadIdx.x;
    if (blockIdx.x < 128) {
        int h  = (t >> 6) & 1;                    // wave-uniform e-half
        int px = (t & 63) | ((t >> 7) << 6);
        int gp = blockIdx.x * 128 + px;           // 0..16383
        int b = gp >> 12, p = gp & 4095;
        int e0 = h * 32;
        float acc[32];
        #pragma unroll
        for (int e = 0; e < 32; e++) acc[e] = 0.f;
        const float* dptr = de + (size_t)b * C * HW + p;
        #pragma unroll 4
        for (int c = 0; c < C; c++) {
            float v = dptr[(size_t)c * HW];
            const float* w = wt_cde + c * EMB + e0;   // wave-uniform -> SMEM
            #pragma unroll
            for (int e = 0; e < 32; e++) acc[e] += w[e] * v;
        }
        float* o = dec + ((size_t)b * EMB + e0) * HW + p;
        #pragma unroll
        for (int e = 0; e < 32; e++) o[(size_t)e * HW] = acc[e];
    } else {
        int gid = (blockIdx.x - 128) * 256 + t;   // 0..16383
        int b = gid >> 12, p = gid & 4095;
        float acc = b_gate[0];
        const float* dptr = de + (size_t)b * C * HW + p;
        #pragma unroll 4
        for (int c = 0; c < C; c++) acc += dptr[(size_t)c * HW] * w_gate[c];
        gate_lr[gid] = 1.f / (1.f + __expf(-acc));
    }
}

// ---------------------------------------------------------------------------
// K3: enc = conv1x1(en, w_cen) + b_cen  (hi-res grid), e-split x2
// ---------------------------------------------------------------------------
__global__ __launch_bounds__(256) void k_enc(
        const float* __restrict__ en, const float* __restrict__ wt_cen,
        const float* __restrict__ b_cen, float* __restrict__ enc) {
    int t = threadIdx.x;
    int h  = (t >> 6) & 1;
    int px = (t & 63) | ((t >> 7) << 6);
    int gp = blockIdx.x * 128 + px;               // 0..65535
    int b = gp >> 14, p = gp & 16383;
    int e0 = h * 32;
    float acc[32];
    #pragma unroll
    for (int e = 0; e < 32; e++) acc[e] = b_cen[e0 + e];
    const float* eptr = en + (size_t)b * C * HWO + p;
    #pragma unroll 4
    for (int c = 0; c < C; c++) {
        float v = eptr[(size_t)c * HWO];
        const float* w = wt_cen + c * EMB + e0;
        #pragma unroll
        for (int e = 0; e < 32; e++) acc[e] += w[e] * v;
    }
    float* o = enc + ((size_t)b * EMB + e0) * HWO + p;
    #pragma unroll
    for (int e = 0; e < 32; e++) o[(size_t)e * HWO] = acc[e];
}

// ---------------------------------------------------------------------------
// K4: 3x3 conv 64->25 (pad=1) with bias, e-split x2 + LDS combine.
//   blocks [0,512):   on enc (128x128) -> tmp1
//   blocks [512,640): on dec (64x64)   -> tmp2
// ---------------------------------------------------------------------------
__global__ __launch_bounds__(256) void k_conv3(
        const float* __restrict__ enc, const float* __restrict__ dec,
        const float* __restrict__ wt_ce, const float* __restrict__ b_ce,
        float* __restrict__ tmp1, float* __restrict__ tmp2) {
    __shared__ float lds[2][128][27];             // 27 pad: odd stride, no 4-way conflicts
    int t = threadIdx.x;
    int h  = (t >> 6) & 1;
    int px = (t & 63) | ((t >> 7) << 6);
    bool hi = blockIdx.x < 512;
    const float* src; float* dst;
    int b, p, y, x, width, hwsz;
    if (hi) {
        int gp = blockIdx.x * 128 + px;
        b = gp >> 14; p = gp & 16383; y = p >> 7; x = p & 127;
        width = WO; hwsz = HWO; src = enc; dst = tmp1;
    } else {
        int gp = (blockIdx.x - 512) * 128 + px;
        b = gp >> 12; p = gp & 4095; y = p >> 6; x = p & 63;
        width = W; hwsz = HW; src = dec; dst = tmp2;
    }
    float acc[25];
    #pragma unroll
    for (int q = 0; q < 25; q++) acc[q] = 0.f;
    const float* sbase = src + ((size_t)b * EMB + h * 32) * hwsz;
    #pragma unroll 2
    for (int e = 0; e < 32; e++) {
        const float* ebase = sbase + (size_t)e * hwsz;
        const float* wbase = wt_ce + ((h * 32 + e) * 9) * 25;
        #pragma unroll
        for (int dy = 0; dy < 3; dy++) {
            int yy = y + dy - 1;
            if ((unsigned)yy < (unsigned)width) {     // square grids: height==width
                #pragma unroll
                for (int dx = 0; dx < 3; dx++) {
                    int xx = x + dx - 1;
                    if ((unsigned)xx < (unsigned)width) {
                        float v = ebase[yy * width + xx];
                        const float* wq = wbase + (dy * 3 + dx) * 25;
                        #pragma unroll
                        for (int q = 0; q < 25; q++) acc[q] += wq[q] * v;
                    }
                }
            }
        }
    }
    #pragma unroll
    for (int q = 0; q < 25; q++) lds[h][px][q] = acc[q];
    __syncthreads();
    if (h == 0) {
        float* o = dst + (size_t)b * 25 * hwsz + p;
        #pragma unroll
        for (int q = 0; q < 25; q++)
            o[(size_t)q * hwsz] = lds[0][px][q] + lds[1][px][q] + b_ce[q];
    }
}

// ---------------------------------------------------------------------------
// K5: softmax over 25 logits per hi-res pixel -> kbuf[b][p][28] (pad 28 for
//     float4 I/O). logits = tmp1[q][p] + tmp2[q][pl] (double-bias matches ref)
// ---------------------------------------------------------------------------
__global__ __launch_bounds__(256) void k_softmax(
        const float* __restrict__ tmp1, const float* __restrict__ tmp2,
        float* __restrict__ kbuf) {
    int gid = blockIdx.x * 256 + threadIdx.x;     // 0..65535 == b*HWO+p
    int b = gid >> 14, p = gid & 16383;
    int i = p >> 7, j = p & 127;
    int pl = (i >> 1) * W + (j >> 1);
    float kern[28];
    float m = -1e30f;
    #pragma unroll
    for (int q = 0; q < 25; q++) {
        float l = tmp1[((size_t)(b * 25 + q) << 14) + p]
                + tmp2[((size_t)(b * 25 + q) << 12) + pl];
        kern[q] = l;
        m = fmaxf(m, l);
    }
    float s = 0.f;
    #pragma unroll
    for (int q = 0; q < 25; q++) { kern[q] = __expf(kern[q] - m); s += kern[q]; }
    float inv = 1.f / s;
    #pragma unroll
    for (int q = 0; q < 25; q++) kern[q] *= inv;
    kern[25] = kern[26] = kern[27] = 0.f;
    float4* o = (float4*)(kbuf + (size_t)gid * 28);
    #pragma unroll
    for (int q = 0; q < 7; q++) o[q] = ((float4*)kern)[q];
}

// ---------------------------------------------------------------------------
// K6: CARAFE + gated blend, tiled & channel-split.
//   grid = (64 tiles, 16 cgroups, 4 batch); block = 256 = 64x4 hi pixels.
//   Each block: stage 36x6 lo-res de halo x 16 ch in LDS, kern in regs.
// ---------------------------------------------------------------------------
#define NCH 16
__global__ __launch_bounds__(256) void k_final(
        const float* __restrict__ en, const float* __restrict__ de,
        const float* __restrict__ kbuf, const float* __restrict__ gate_lr,
        float* __restrict__ out) {
    __shared__ float sde[NCH][6][36];             // 13824 B
    int t = threadIdx.x;
    int tx = t & 63, ty = t >> 6;
    int tileX = blockIdx.x & 1;                   // 2 x-tiles (64 wide)
    int tileY = blockIdx.x >> 1;                  // 32 y-tiles (4 tall)
    int c0 = blockIdx.y * NCH;
    int b = blockIdx.z;
    int i0 = tileY * 4, j0 = tileX * 64;
    int yl0 = i0 >> 1, xl0 = j0 >> 1;

    // stage de halo window: rows yl0-2..yl0+3, cols xl0-2..xl0+33
    const float* dbase = de + ((size_t)b * C + c0) * HW;
    for (int idx = t; idx < NCH * 216; idx += 256) {
        int c = idx / 216, r = idx % 216;
        int y = r / 36, x = r % 36;
        int yy = yl0 - 2 + y, xx = xl0 - 2 + x;
        float v = 0.f;
        if ((unsigned)yy < (unsigned)H && (unsigned)xx < (unsigned)W)
            v = dbase[(size_t)c * HW + yy * W + xx];
        ((float*)sde)[idx] = v;
    }

    int i = i0 + ty, j = j0 + tx;
    int p = i * WO + j;
    float kern[28];
    const float4* kb = (const float4*)(kbuf + ((size_t)(b * HWO + p)) * 28);
    #pragma unroll
    for (int q = 0; q < 7; q++) ((float4*)kern)[q] = kb[q];
    float g = gate_lr[b * HW + (i >> 1) * W + (j >> 1)];
    __syncthreads();

    int wy = ty >> 1, wx = tx >> 1;               // lo offset within tile
    const float* ebase = en + ((size_t)b * C + c0) * HWO + p;
    float* obase = out + ((size_t)b * C + c0) * HWO + p;
    #pragma unroll 2
    for (int c = 0; c < NCH; c++) {
        float acc = 0.f;
        #pragma unroll
        for (int dy = 0; dy < 5; dy++) {
            #pragma unroll
            for (int dx = 0; dx < 5; dx++)
                acc += kern[dy * 5 + dx] * sde[c][wy + dy][wx + dx];
        }
        float ev = ebase[(size_t)c * HWO];
        obase[(size_t)c * HWO] = g * ev + (1.f - g) * acc;
    }
}

extern "C" void kernel_launch(void* const* d_in, const int* in_sizes, int n_in,
                              void* d_out, int out_size, void* d_ws, size_t ws_size,
                              hipStream_t stream) {
    const float* en     = (const float*)d_in[0];
    const float* de     = (const float*)d_in[1];
    const float* w_gate = (const float*)d_in[2];
    const float* b_gate = (const float*)d_in[3];
    const float* w_cen  = (const float*)d_in[4];
    const float* b_cen  = (const float*)d_in[5];
    const float* w_cde  = (const float*)d_in[6];
    const float* w_ce   = (const float*)d_in[7];
    const float* b_ce   = (const float*)d_in[8];
    float* out = (float*)d_out;

    float* ws      = (float*)d_ws;
    float* wt_cen  = ws;                    // 16384
    float* wt_cde  = wt_cen + 16384;        // 16384
    float* wt_ce   = wt_cde + 16384;        // 14400
    float* gate_lr = wt_ce + 14400;         // 16384
    float* dec     = gate_lr + 16384;       // 4*64*4096   = 1048576
    float* enc     = dec + 1048576;         // 4*64*16384  = 4194304
    float* tmp1    = enc + 4194304;         // 4*25*16384  = 1638400
    float* tmp2    = tmp1 + 1638400;        // 4*25*4096   = 409600
    float* kbuf    = enc;                   // alias: enc dead after k_conv3
                                            // needs 4*16384*28 = 1835008 < 4194304

    k_prep<<<64, 256, 0, stream>>>(w_cen, w_cde, w_ce, wt_cen, wt_cde, wt_ce);
    k_dec_gate<<<192, 256, 0, stream>>>(de, wt_cde, w_gate, b_gate, dec, gate_lr);
    k_enc<<<512, 256, 0, stream>>>(en, wt_cen, b_cen, enc);
    k_conv3<<<640, 256, 0, stream>>>(enc, dec, wt_ce, b_ce, tmp1, tmp2);
    k_softmax<<<256, 256, 0, stream>>>(tmp1, tmp2, kbuf);
    k_final<<<dim3(64, 16, 4), 256, 0, stream>>>(en, de, kbuf, gate_lr, out);
}

// Round 3
// 240.027 us; speedup vs baseline: 4.9223x; 2.5411x over previous
//
#include <hip/hip_runtime.h>
#include <math.h>

#define BB 4
#define C 256
#define H 64
#define W 64
#define HW 4096
#define HO 128
#define WO 128
#define HWO 16384
#define EMB 64

typedef __bf16 bf16x8 __attribute__((ext_vector_type(8)));
typedef __bf16 bf16x4 __attribute__((ext_vector_type(4)));
typedef float  f32x4  __attribute__((ext_vector_type(4)));

__device__ __forceinline__ f32x4 mfma16(bf16x8 a, bf16x8 b, f32x4 c) {
    return __builtin_amdgcn_mfma_f32_16x16x32_bf16(a, b, c, 0, 0, 0);
}

// ---------------------------------------------------------------------------
// K1: prep weight tables (bf16) in MFMA-friendly layouts
//   wbf_cen/wbf_cde: [e][c]  (A-frag rows c-contiguous)
//   w3: [tap9][mt2][m16][e64], rows m>=25 zeroed
// ---------------------------------------------------------------------------
__global__ void k_prep2(const float* __restrict__ w_cen,
                        const float* __restrict__ w_cde,
                        const float* __restrict__ w_ce,
                        __bf16* __restrict__ wbf_cen,
                        __bf16* __restrict__ wbf_cde,
                        __bf16* __restrict__ w3) {
    const int n1 = EMB * C;            // 16384, layout already [e][c]
    const int n3 = 9 * 2 * 16 * EMB;   // 18432
    for (int idx = blockIdx.x * blockDim.x + threadIdx.x; idx < n1;
         idx += gridDim.x * blockDim.x) {
        wbf_cen[idx] = (__bf16)w_cen[idx];
        wbf_cde[idx] = (__bf16)w_cde[idx];
    }
    for (int idx = blockIdx.x * blockDim.x + threadIdx.x; idx < n3;
         idx += gridDim.x * blockDim.x) {
        int e = idx & 63;
        int m = (idx >> 6) & 15;
        int mt = (idx >> 10) & 1;
        int tap = idx >> 11;
        int q = mt * 16 + m;
        int dy = tap / 3, dx = tap % 3;
        w3[idx] = (q < 25) ? (__bf16)w_ce[((q * EMB + e) * 3 + dy) * 3 + dx]
                           : (__bf16)0.0f;
    }
}

// ---------------------------------------------------------------------------
// K2: MFMA GEMM  Y[px][e] = sum_c Wt[e][c] * X[c][px]   (bf16 in, fp32 acc)
//   blocks [0,512): enc (adds b_cen);  [512,640): dec (no bias)
//   block = 128 px tile, 4 waves x (2 n-tiles x 4 m-tiles), K=256
// ---------------------------------------------------------------------------
__global__ __launch_bounds__(256) void k_gemm1(
        const float* __restrict__ en, const float* __restrict__ de,
        const __bf16* __restrict__ wbf_cen, const __bf16* __restrict__ wbf_cde,
        const float* __restrict__ b_cen,
        __bf16* __restrict__ enc_t, __bf16* __restrict__ dec_t) {
    int t = threadIdx.x;
    int w = t >> 6, lane = t & 63;
    int n = lane & 15, q = lane >> 4;
    bool isenc = blockIdx.x < 512;
    const float* X; const __bf16* Wt; __bf16* Y; int plane, px0;
    if (isenc) {
        int blk = blockIdx.x; int b = blk >> 7; px0 = (blk & 127) << 7;
        X = en + (size_t)b * C * HWO; plane = HWO; Wt = wbf_cen;
        Y = enc_t + (size_t)b * HWO * EMB;
    } else {
        int blk = blockIdx.x - 512; int b = blk >> 5; px0 = (blk & 31) << 7;
        X = de + (size_t)b * C * HW; plane = HW; Wt = wbf_cde;
        Y = dec_t + (size_t)b * HW * EMB;
    }
    int pxw = px0 + w * 32;
    f32x4 acc[4][2] = {};
    for (int kc = 0; kc < 8; kc++) {
        int c0 = kc * 32;
        bf16x8 af[4];
        #pragma unroll
        for (int mt = 0; mt < 4; mt++)
            af[mt] = *(const bf16x8*)(Wt + (mt * 16 + n) * C + c0 + q * 8);
        #pragma unroll
        for (int nt = 0; nt < 2; nt++) {
            int px = pxw + nt * 16 + n;
            bf16x8 bv;
            #pragma unroll
            for (int j = 0; j < 8; j++)
                bv[j] = (__bf16)X[(size_t)(c0 + q * 8 + j) * plane + px];
            #pragma unroll
            for (int mt = 0; mt < 4; mt++)
                acc[mt][nt] = mfma16(af[mt], bv, acc[mt][nt]);
        }
    }
    #pragma unroll
    for (int mt = 0; mt < 4; mt++) {
        int e0 = mt * 16 + q * 4;
        float bias[4];
        #pragma unroll
        for (int r = 0; r < 4; r++) bias[r] = isenc ? b_cen[e0 + r] : 0.f;
        #pragma unroll
        for (int nt = 0; nt < 2; nt++) {
            int px = pxw + nt * 16 + n;
            bf16x4 ov;
            #pragma unroll
            for (int r = 0; r < 4; r++)
                ov[r] = (__bf16)(acc[mt][nt][r] + bias[r]);
            *(bf16x4*)(Y + (size_t)px * EMB + e0) = ov;
        }
    }
}

// ---------------------------------------------------------------------------
// K3: gate = sigmoid(conv1x1(de, w_gate)+b_gate); 64px x 4-way c-split/block
// ---------------------------------------------------------------------------
__global__ __launch_bounds__(256) void k_gate(
        const float* __restrict__ de, const float* __restrict__ w_gate,
        const float* __restrict__ b_gate, float* __restrict__ gate_lr) {
    __shared__ float red[4][64];
    int t = threadIdx.x;
    int px = t & 63, cs = t >> 6;
    int b = blockIdx.x >> 6, p0 = (blockIdx.x & 63) * 64;
    const float* dptr = de + ((size_t)b * C + cs * 64) * HW + p0 + px;
    float s = 0.f;
    #pragma unroll 4
    for (int c = 0; c < 64; c++)
        s += dptr[(size_t)c * HW] * w_gate[cs * 64 + c];
    red[cs][px] = s;
    __syncthreads();
    if (t < 64) {
        float v = red[0][t] + red[1][t] + red[2][t] + red[3][t] + b_gate[0];
        gate_lr[b * HW + p0 + t] = 1.f / (1.f + __expf(-v));
    }
}

// ---------------------------------------------------------------------------
// K4: 3x3 conv 64->25 via MFMA (9 shifted GEMMs, K=64), bias added.
//   blocks [0,1024): on enc_t (128x128) -> tmp1
//   blocks [1024,1280): on dec_t (64x64) -> tmp2
//   block = 64-px row segment, 4 waves x 16 px, 2 m-tiles
// ---------------------------------------------------------------------------
__global__ __launch_bounds__(256) void k_conv3m(
        const __bf16* __restrict__ enc_t, const __bf16* __restrict__ dec_t,
        const __bf16* __restrict__ w3, const float* __restrict__ b_ce,
        float* __restrict__ tmp1, float* __restrict__ tmp2) {
    int t = threadIdx.x;
    int w = t >> 6, lane = t & 63;
    int n = lane & 15, q = lane >> 4;
    bool hi = blockIdx.x < 1024;
    const __bf16* src; float* dst; int b, y, width, plane, x;
    if (hi) {
        int blk = blockIdx.x; b = blk >> 8; int r = blk & 255;
        y = r >> 1; int seg = r & 1;
        width = WO; plane = HWO;
        src = enc_t + (size_t)b * HWO * EMB; dst = tmp1;
        x = seg * 64 + w * 16 + n;
    } else {
        int blk = blockIdx.x - 1024; b = blk >> 6; y = blk & 63;
        width = W; plane = HW;
        src = dec_t + (size_t)b * HW * EMB; dst = tmp2;
        x = w * 16 + n;
    }
    f32x4 acc[2] = {};
    bf16x8 bz;
    #pragma unroll
    for (int j = 0; j < 8; j++) bz[j] = (__bf16)0.0f;
    #pragma unroll
    for (int dy = -1; dy <= 1; dy++) {
        int yy = y + dy;
        if ((unsigned)yy >= (unsigned)width) continue;   // wave-uniform
        #pragma unroll
        for (int dx = -1; dx <= 1; dx++) {
            int tap = (dy + 1) * 3 + (dx + 1);
            int xx = x + dx;
            bool valid = (unsigned)xx < (unsigned)width;
            int xc = valid ? xx : 0;
            const __bf16* brow = src + ((size_t)yy * width + xc) * EMB;
            #pragma unroll
            for (int kc = 0; kc < 2; kc++) {
                bf16x8 bv = *(const bf16x8*)(brow + kc * 32 + q * 8);
                if (!valid) bv = bz;
                #pragma unroll
                for (int mt = 0; mt < 2; mt++) {
                    bf16x8 av = *(const bf16x8*)(
                        w3 + ((tap * 2 + mt) * 16 + n) * EMB + kc * 32 + q * 8);
                    acc[mt] = mfma16(av, bv, acc[mt]);
                }
            }
        }
    }
    #pragma unroll
    for (int mt = 0; mt < 2; mt++) {
        #pragma unroll
        for (int r = 0; r < 4; r++) {
            int m = mt * 16 + q * 4 + r;
            if (m < 25)
                dst[((size_t)(b * 25 + m)) * plane + y * width + x] =
                    acc[mt][r] + b_ce[m];
        }
    }
}

// ---------------------------------------------------------------------------
// K5: softmax over 25 logits per hi-res pixel -> kbuf[b][p][28]
// ---------------------------------------------------------------------------
__global__ __launch_bounds__(256) void k_softmax(
        const float* __restrict__ tmp1, const float* __restrict__ tmp2,
        float* __restrict__ kbuf) {
    int gid = blockIdx.x * 256 + threadIdx.x;     // 0..65535 == b*HWO+p
    int b = gid >> 14, p = gid & 16383;
    int i = p >> 7, j = p & 127;
    int pl = (i >> 1) * W + (j >> 1);
    float kern[28];
    float m = -1e30f;
    #pragma unroll
    for (int q = 0; q < 25; q++) {
        float l = tmp1[((size_t)(b * 25 + q) << 14) + p]
                + tmp2[((size_t)(b * 25 + q) << 12) + pl];
        kern[q] = l;
        m = fmaxf(m, l);
    }
    float s = 0.f;
    #pragma unroll
    for (int q = 0; q < 25; q++) { kern[q] = __expf(kern[q] - m); s += kern[q]; }
    float inv = 1.f / s;
    #pragma unroll
    for (int q = 0; q < 25; q++) kern[q] *= inv;
    kern[25] = kern[26] = kern[27] = 0.f;
    float4* o = (float4*)(kbuf + (size_t)gid * 28);
    #pragma unroll
    for (int q = 0; q < 7; q++) o[q] = ((float4*)kern)[q];
}

// ---------------------------------------------------------------------------
// K6: CARAFE + gated blend, tiled & channel-split (fp32).
// ---------------------------------------------------------------------------
#define NCH 16
__global__ __launch_bounds__(256) void k_final(
        const float* __restrict__ en, const float* __restrict__ de,
        const float* __restrict__ kbuf, const float* __restrict__ gate_lr,
        float* __restrict__ out) {
    __shared__ float sde[NCH][6][36];             // 13824 B
    int t = threadIdx.x;
    int tx = t & 63, ty = t >> 6;
    int tileX = blockIdx.x & 1;
    int tileY = blockIdx.x >> 1;
    int c0 = blockIdx.y * NCH;
    int b = blockIdx.z;
    int i0 = tileY * 4, j0 = tileX * 64;
    int yl0 = i0 >> 1, xl0 = j0 >> 1;

    const float* dbase = de + ((size_t)b * C + c0) * HW;
    for (int idx = t; idx < NCH * 216; idx += 256) {
        int c = idx / 216, r = idx % 216;
        int y = r / 36, x = r % 36;
        int yy = yl0 - 2 + y, xx = xl0 - 2 + x;
        float v = 0.f;
        if ((unsigned)yy < (unsigned)H && (unsigned)xx < (unsigned)W)
            v = dbase[(size_t)c * HW + yy * W + xx];
        ((float*)sde)[idx] = v;
    }

    int i = i0 + ty, j = j0 + tx;
    int p = i * WO + j;
    float kern[28];
    const float4* kb = (const float4*)(kbuf + ((size_t)(b * HWO + p)) * 28);
    #pragma unroll
    for (int q = 0; q < 7; q++) ((float4*)kern)[q] = kb[q];
    float g = gate_lr[b * HW + (i >> 1) * W + (j >> 1)];
    __syncthreads();

    int wy = ty >> 1, wx = tx >> 1;
    const float* ebase = en + ((size_t)b * C + c0) * HWO + p;
    float* obase = out + ((size_t)b * C + c0) * HWO + p;
    #pragma unroll 2
    for (int c = 0; c < NCH; c++) {
        float acc = 0.f;
        #pragma unroll
        for (int dy = 0; dy < 5; dy++) {
            #pragma unroll
            for (int dx = 0; dx < 5; dx++)
                acc += kern[dy * 5 + dx] * sde[c][wy + dy][wx + dx];
        }
        float ev = ebase[(size_t)c * HWO];
        obase[(size_t)c * HWO] = g * ev + (1.f - g) * acc;
    }
}

extern "C" void kernel_launch(void* const* d_in, const int* in_sizes, int n_in,
                              void* d_out, int out_size, void* d_ws, size_t ws_size,
                              hipStream_t stream) {
    const float* en     = (const float*)d_in[0];
    const float* de     = (const float*)d_in[1];
    const float* w_gate = (const float*)d_in[2];
    const float* b_gate = (const float*)d_in[3];
    const float* w_cen  = (const float*)d_in[4];
    const float* b_cen  = (const float*)d_in[5];
    const float* w_cde  = (const float*)d_in[6];
    const float* w_ce   = (const float*)d_in[7];
    const float* b_ce   = (const float*)d_in[8];
    float* out = (float*)d_out;

    // bf16 region
    __bf16* wsb    = (__bf16*)d_ws;
    __bf16* wbf_cen = wsb;                   // 16384
    __bf16* wbf_cde = wbf_cen + 16384;       // 16384
    __bf16* w3      = wbf_cde + 16384;       // 18432
    __bf16* enc_t   = w3 + 18432;            // 65536*64 = 4194304
    __bf16* dec_t   = enc_t + 4194304;       // 16384*64 = 1048576
    // fp32 region (16B-aligned: 10588160 bytes offset)
    float* wsf     = (float*)((char*)d_ws + (size_t)(16384 + 16384 + 18432
                              + 4194304 + 1048576) * 2);
    float* tmp1    = wsf;                    // 4*25*16384 = 1638400
    float* tmp2    = tmp1 + 1638400;         // 4*25*4096  = 409600
    float* gate_lr = tmp2 + 409600;          // 16384
    float* kbuf    = gate_lr + 16384;        // 4*16384*28 = 1835008
    // total ~26.2 MB

    k_prep2<<<72, 256, 0, stream>>>(w_cen, w_cde, w_ce, wbf_cen, wbf_cde, w3);
    k_gemm1<<<640, 256, 0, stream>>>(en, de, wbf_cen, wbf_cde, b_cen, enc_t, dec_t);
    k_gate<<<256, 256, 0, stream>>>(de, w_gate, b_gate, gate_lr);
    k_conv3m<<<1280, 256, 0, stream>>>(enc_t, dec_t, w3, b_ce, tmp1, tmp2);
    k_softmax<<<256, 256, 0, stream>>>(tmp1, tmp2, kbuf);
    k_final<<<dim3(64, 16, 4), 256, 0, stream>>>(en, de, kbuf, gate_lr, out);
}